// Round 3
// baseline (26017.346 us; speedup 1.0000x reference)
//
#include <hip/hip_runtime.h>
#include <stdint.h>

// ============================================================================
// Persistent-RNN kernel for RecBlock: 2048 sequential steps. BN batch stats
// are the only cross-wg coupling.
//
// Partition: 128 persistent workgroups = 16 row-groups (16 batch rows each)
//            x 8 col-groups (32 hidden cols each; 16 output cols each).
// Weights (W_ih slice, W_ho slice) live in LDS for the whole kernel as
// bf16 hi/lo pairs; GEMMs run on v_mfma_f32_16x16x32_bf16 with a 3-term
// hi/lo expansion (hi*hi + hi*lo + lo*hi) for near-fp32 accuracy.
//
// Sync design (v2.1): NO device-wide barrier. All cross-wg exchange is
// tagged-data dataflow (RCCL-LL style):
//  * every exchanged float is an 8B (payload, step_tag) word stored with one
//    agent-scope (sc1) store -> single-copy atomic at the MALL. No fences,
//    no vmcnt drain, no flag, no L2 writeback/invalidate.
//  * consumers issue all poll loads right after their own stores, hide the
//    latency under the (now pipelined) output GEMM + X prefetch, and re-load
//    only stale words until tags match t+1.
//  * overwrite safety of the parity-2 buffers: a wg reaches step t+2 only
//    after observing tag t+2 from EVERY wg, which each wg publishes only
//    after fully completing step t (incl. its tag-t+1 reads). Monotonic tags,
//    workspace zeroed by init_tags each launch (covers harness poisoning).
//  * retry loops are BOUNDED (never legitimately trips; converts any latent
//    protocol bug into a wrong answer instead of a hung container).
//
// Software pipeline: out-GEMM for step t-1 runs AFTER step t's z publish
// (off the recurrence critical path); its cross-wave reduce reuses S4.
// Barriers per step: S1 (z reduce), S4 (stats/red2), S5 (h ready). 
//
// b_ih is omitted: a per-column constant cancels exactly in (z - mean(z)).
// ============================================================================

#define S_LEN 2048
#define BATCH 256
#define NIN   128
#define HID   256
#define NOUT  128

#define NBLK  128   // 16 row-groups x 8 col-groups (1 block/CU by LDS)
#define NTHR  256   // 4 waves
#define NR    16    // batch rows per wg
#define NC    32    // z columns per wg
#define NO    16    // output columns per wg

#define HXW   392   // padded k-stride (shorts) for hx and W_ih slices (384+8)
#define WHOW  264   // padded k-stride (shorts) for W_ho slice (256+8)

#define SPIN_MAX (1u<<16)   // ~4M cycles with s_sleep(1); legit skew is <10us

typedef short short8  __attribute__((ext_vector_type(8)));
typedef float float4v __attribute__((ext_vector_type(4)));
typedef unsigned long long u64;

// LDS layout (in shorts for the bf16 region, floats after)
#define HXHI_OFF  0
#define HXLO_OFF  (16*HXW)
#define WHI_OFF   (2*16*HXW)
#define WLO_OFF   (2*16*HXW + 32*HXW)
#define WHOHI_OFF (2*16*HXW + 2*32*HXW)
#define WHOLO_OFF (WHOHI_OFF + 16*WHOW)
#define SHORTS_TOTAL (WHOLO_OFF + 16*WHOW)      // 46080 shorts = 92160 B
#define RED_F 1088                               // 4 x 16 x 17 floats
#define SMEM_BYTES (SHORTS_TOTAL*2 + (2*RED_F + 256 + 256 + 16)*4)  // 102976 B

// workspace layout (u64 units):
//   partials: [2][16 rowg][256 col][2]  (sum,tag),(sumsq,tag)   16384 u64
//   zbuf:     [2][256 row][256 col]     (z,tag)                131072 u64
#define PART_U64 (2*16*256*2)
#define ZBUF_U64 (2*BATCH*HID)
#define WS_U64   (PART_U64 + ZBUF_U64)           // 147456 u64 = 1.125 MB

#define MFMA(a,b,c) __builtin_amdgcn_mfma_f32_16x16x32_bf16(a,b,c,0,0,0)

#define AG_ST(p, v) __hip_atomic_store((p), (v), __ATOMIC_RELAXED, __HIP_MEMORY_SCOPE_AGENT)
#define AG_LD(p)    __hip_atomic_load((p), __ATOMIC_RELAXED, __HIP_MEMORY_SCOPE_AGENT)

__device__ __forceinline__ u64 packft(float f, unsigned tag) {
  return (u64)__float_as_uint(f) | ((u64)tag << 32);
}
__device__ __forceinline__ float lo_f(u64 v) { return __uint_as_float((unsigned)v); }
__device__ __forceinline__ unsigned hi_t(u64 v) { return (unsigned)(v >> 32); }

__device__ __forceinline__ short f2bf(float f) {
  unsigned u = __float_as_uint(f);
  unsigned r = (u + 0x7fffu + ((u >> 16) & 1u)) >> 16;  // RNE
  return (short)r;
}
__device__ __forceinline__ float bf2f(short s) {
  return __uint_as_float(((unsigned)(unsigned short)s) << 16);
}
__device__ __forceinline__ float gelu_f(float x) {
  return 0.5f * x * (1.0f + erff(x * 0.70710678118654752f));
}

// stage X[:, t, :] slice (16 rows x 128) into hx bf16 hi/lo
__device__ __forceinline__ void stage_x(const float* __restrict__ X,
                                        short* hx_hi, short* hx_lo,
                                        int r0, int t, int tid) {
  int row = tid >> 4;           // 0..15
  int k0  = (tid & 15) * 8;     // 0..120
  const float* xp = X + ((size_t)(r0 + row) * S_LEN + t) * NIN + k0;
  float4v a = *(const float4v*)xp;
  float4v b = *(const float4v*)(xp + 4);
  short8 hi, lo;
#pragma unroll
  for (int j = 0; j < 4; ++j) {
    short h1 = f2bf(a[j]); hi[j] = h1; lo[j] = f2bf(a[j] - bf2f(h1));
  }
#pragma unroll
  for (int j = 0; j < 4; ++j) {
    short h1 = f2bf(b[j]); hi[4+j] = h1; lo[4+j] = f2bf(b[j] - bf2f(h1));
  }
  *(short8*)(hx_hi + row*HXW + k0) = hi;
  *(short8*)(hx_lo + row*HXW + k0) = lo;
}

// out-GEMM MFMA phase: o-partial for K-quarter wv -> red2 (reads hx h-region)
__device__ __forceinline__ void out_gemm_mfma(const short* hx_hi, const short* hx_lo,
                                              const short* who_hi, const short* who_lo,
                                              float* red2, int wv, int nn, int quad) {
  float4v oacc = {0.f, 0.f, 0.f, 0.f};
  const short* arow_hi = hx_hi + nn*HXW + 128;
  const short* arow_lo = hx_lo + nn*HXW + 128;
  const short* brow_hi = who_hi + nn*WHOW;
  const short* brow_lo = who_lo + nn*WHOW;
  int kb = wv*64 + quad*8;
#pragma unroll
  for (int ks = 0; ks < 2; ++ks) {
    short8 ah = *(const short8*)(arow_hi + kb);
    short8 al = *(const short8*)(arow_lo + kb);
    short8 bh = *(const short8*)(brow_hi + kb);
    short8 bl = *(const short8*)(brow_lo + kb);
    oacc = MFMA(ah, bh, oacc);
    oacc = MFMA(ah, bl, oacc);
    oacc = MFMA(al, bh, oacc);
    kb += 32;
  }
#pragma unroll
  for (int i = 0; i < 4; ++i) red2[wv*272 + (quad*4 + i)*17 + nn] = oacc[i];
}

__device__ __forceinline__ void out_write(const float* red2, const float* sbho,
                                          float* __restrict__ out,
                                          int r0, int oc0, int t, int tid) {
  int row = tid >> 4, col = tid & 15;
  float v = red2[0*272 + row*17 + col] + red2[1*272 + row*17 + col]
          + red2[2*272 + row*17 + col] + red2[3*272 + row*17 + col]
          + sbho[col];
  out[((size_t)(r0 + row) * S_LEN + t) * NOUT + oc0 + col] = gelu_f(v);
}

__global__ void init_tags(u64* ws) {
  // agent-scope stores so the zero tags land at the MALL, not as dirty
  // lines in one XCD's L2 (plain stores would be invisible to sc1 loads).
  for (int i = blockIdx.x * blockDim.x + threadIdx.x; i < WS_U64;
       i += gridDim.x * blockDim.x)
    AG_ST(ws + i, 0ull);
}

__global__ void __launch_bounds__(NTHR, 1)
rec_kernel(const float* __restrict__ X, const float* __restrict__ W_ih,
           const float* __restrict__ W_ho, const float* __restrict__ b_ho,
           const float* __restrict__ gamma, const float* __restrict__ beta,
           float* __restrict__ out,
           u64* __restrict__ part, u64* __restrict__ zbuf)
{
  extern __shared__ char smemraw[];
  short* sh      = (short*)smemraw;
  short* hx_hi   = sh + HXHI_OFF;   // [16][HXW]  k: 0..127 = x_t, 128..383 = h_t
  short* hx_lo   = sh + HXLO_OFF;
  short* w_hi    = sh + WHI_OFF;    // [32][HXW]  W_ih rows c0..c0+31
  short* w_lo    = sh + WLO_OFF;
  short* who_hi  = sh + WHOHI_OFF;  // [16][WHOW] W_ho rows oc0..oc0+15
  short* who_lo  = sh + WHOLO_OFF;
  float* red     = (float*)(sh + SHORTS_TOTAL); // z-GEMM cross-wave reduce
  float* red2    = red + RED_F;     // [4][16][17] out-GEMM reduce (own region)
  float* sscale  = red2 + RED_F;    // [256] BN scale per column
  float* sshift  = sscale + 256;    // [256] BN shift per column
  float* sbho    = sshift + 256;    // [16]

  const int tid   = threadIdx.x;
  const int rowg  = blockIdx.x >> 3;   // 0..15
  const int colg  = blockIdx.x & 7;    // 0..7
  const int r0    = rowg * NR;
  const int c0    = colg * NC;
  const int oc0   = colg * NO;
  const int wv    = tid >> 6;          // wave 0..3
  const int lane  = tid & 63;
  const int nn    = lane & 15;         // MFMA m / n index
  const int quad  = lane >> 4;         // MFMA k-group / row-group
  const int sub   = wv >> 1;           // z col-subtile 0/1
  const int khalf = wv & 1;            // K half for z-GEMM

  // ---- one-time init: stage weight slices into LDS as bf16 hi/lo ----
  for (int idx = tid; idx < NC * 384; idx += NTHR) {
    int r = idx / 384, j = idx % 384;
    float w = W_ih[(size_t)(c0 + r) * 384 + j];
    short hi = f2bf(w);
    w_hi[r*HXW + j] = hi;
    w_lo[r*HXW + j] = f2bf(w - bf2f(hi));
  }
  for (int idx = tid; idx < NO * 256; idx += NTHR) {
    int r = idx / 256, j = idx % 256;
    float w = W_ho[(size_t)(oc0 + r) * 256 + j];
    short hi = f2bf(w);
    who_hi[r*WHOW + j] = hi;
    who_lo[r*WHOW + j] = f2bf(w - bf2f(hi));
  }
  if (tid < NO) sbho[tid] = b_ho[oc0 + tid];
  // h0 = 0: zero the h region of hx (k in [128, 392))
  for (int idx = tid; idx < 16 * 33; idx += NTHR) {
    int row = idx / 33, k0 = 128 + (idx % 33) * 8;
    short8 z8 = {0,0,0,0,0,0,0,0};
    *(short8*)(hx_hi + row*HXW + k0) = z8;
    *(short8*)(hx_lo + row*HXW + k0) = z8;
  }
  stage_x(X, hx_hi, hx_lo, r0, 0, tid);

  const float g_gamma = gamma[tid];   // loop-invariant (tid = BN column)
  const float g_beta  = beta[tid];
  __syncthreads();

  // consumer poll geometry (fixed per thread)
  const int zrow = tid >> 4;            // row within our 16
  const int zcb  = (tid & 15) * 16;     // 16 contiguous cols per thread

  for (int t = 0; t < S_LEN; ++t) {
    const int p = t & 1;
    u64* partp = part + (size_t)p * (16*256*2);
    u64* zbp   = zbuf + (size_t)p * (BATCH*HID);
    const unsigned tag = (unsigned)(t + 1);

    // ---- z-GEMM: z[r0..r0+15][c0+sub*16 .. +16) over K half ----
    float4v acc = {0.f, 0.f, 0.f, 0.f};
    {
      const short* arow_hi = hx_hi + nn*HXW;             // A row m = nn
      const short* arow_lo = hx_lo + nn*HXW;
      const short* brow_hi = w_hi + (sub*16 + nn)*HXW;   // B col n = nn
      const short* brow_lo = w_lo + (sub*16 + nn)*HXW;
      int kb = khalf*192 + quad*8;
#pragma unroll
      for (int ks = 0; ks < 6; ++ks) {
        short8 ah = *(const short8*)(arow_hi + kb);
        short8 al = *(const short8*)(arow_lo + kb);
        short8 bh = *(const short8*)(brow_hi + kb);
        short8 bl = *(const short8*)(brow_lo + kb);
        acc = MFMA(ah, bh, acc);
        acc = MFMA(ah, bl, acc);
        acc = MFMA(al, bh, acc);
        kb += 32;
      }
    }
    if (khalf == 1) {   // publish K-half-1 partial for cross-wave reduce
#pragma unroll
      for (int i = 0; i < 4; ++i) red[sub*272 + (quad*4 + i)*17 + nn] = acc[i];
    }
    __syncthreads();  // S1
    if (khalf == 0) {
#pragma unroll
      for (int i = 0; i < 4; ++i) acc[i] += red[sub*272 + (quad*4 + i)*17 + nn];
      // tagged z stores: 8B (payload, step tag), single-copy atomic at MALL
      u64* zb = zbp + (size_t)(r0 + quad*4) * HID + (c0 + sub*16 + nn);
#pragma unroll
      for (int i = 0; i < 4; ++i) AG_ST(zb + i*HID, packft(acc[i], tag));
      // per-column partial sums over our 16 rows
      float s = acc[0] + acc[1] + acc[2] + acc[3];
      float q = acc[0]*acc[0] + acc[1]*acc[1] + acc[2]*acc[2] + acc[3]*acc[3];
      s += __shfl_down(s, 32);  q += __shfl_down(q, 32);
      s += __shfl_down(s, 16);  q += __shfl_down(q, 16);
      if (lane < 16) {
        int c = c0 + sub*16 + lane;
        u64* pe = partp + ((size_t)rowg*256 + c)*2;
        AG_ST(pe,     packft(s, tag));
        AG_ST(pe + 1, packft(q, tag));
      }
    }
    // Publish done (fire-and-forget; tags carry arrival). Issue all consumer
    // poll loads now, then fill the latency shadow with pipelined work.
    const u64* zp = zbp + (size_t)(r0 + zrow) * HID + zcb;
    u64 zv[16], pv[16], qv[16];
#pragma unroll
    for (int j = 0; j < 16; ++j) zv[j] = AG_LD(zp + j);
#pragma unroll
    for (int rg = 0; rg < 16; ++rg) {
      const u64* pe = partp + ((size_t)rg*256 + tid)*2;
      pv[rg] = AG_LD(pe);
      qv[rg] = AG_LD(pe + 1);
    }

    // ---- pipelined out-GEMM for step t-1 (reads h(t); off critical path;
    //      h-region is overwritten only after S4) ----
    if (t > 0)
      out_gemm_mfma(hx_hi, hx_lo, who_hi, who_lo, red2, wv, nn, quad);

    // prefetch next X slice into hx x-region (z-GEMM x-reads were pre-S1)
    if (t + 1 < S_LEN) stage_x(X, hx_hi, hx_lo, r0, t + 1, tid);

    // ---- retry stale partials (stats dependency comes first; bounded) ----
    {
      unsigned spin = 0;
      for (;;) {
        bool ok = true;
#pragma unroll
        for (int rg = 0; rg < 16; ++rg) {
          const u64* pe = partp + ((size_t)rg*256 + tid)*2;
          if (hi_t(pv[rg]) != tag) { ok = false; pv[rg] = AG_LD(pe); }
          if (hi_t(qv[rg]) != tag) { ok = false; qv[rg] = AG_LD(pe + 1); }
        }
        if (ok || ++spin > SPIN_MAX) break;
        __builtin_amdgcn_s_sleep(1);
      }
    }

    // ---- stats: this thread = BN column tid (same sum order as before) ----
    {
      float sA = 0.f, sB = 0.f;
#pragma unroll
      for (int rg = 0; rg < 16; ++rg) { sA += lo_f(pv[rg]); sB += lo_f(qv[rg]); }
      float mu   = sA * (1.0f/256.0f);
      float var  = sB * (1.0f/256.0f) - mu*mu;    // biased, matches BN training
      float rstd = rsqrtf(var + 1e-5f);
      float g    = g_gamma * rstd;
      sscale[tid] = g;
      sshift[tid] = g_beta - mu * g;
    }
    __syncthreads();  // S4 (also orders red2 writes above vs reduce below)

    // ---- finish step t-1 output: reduce red2, bias, GELU, store ----
    if (t > 0) out_write(red2, sbho, out, r0, oc0, t - 1, tid);

    // ---- retry stale zbuf words (latency hid under out-GEMM/stats) ----
    {
      unsigned spin = 0;
      for (;;) {
        bool ok = true;
#pragma unroll
        for (int j = 0; j < 16; ++j)
          if (hi_t(zv[j]) != tag) { ok = false; zv[j] = AG_LD(zp + j); }
        if (ok || ++spin > SPIN_MAX) break;
        __builtin_amdgcn_s_sleep(1);
      }
    }

    // ---- reconstruct h(t+1) for our 16 full rows: BN + exact GELU ----
    {
      short hb[16], lb[16];
#pragma unroll
      for (int j = 0; j < 16; ++j) {
        float z  = lo_f(zv[j]);
        float zn = z * sscale[zcb + j] + sshift[zcb + j];
        float h  = gelu_f(zn);
        short hh = f2bf(h);
        hb[j] = hh; lb[j] = f2bf(h - bf2f(hh));
      }
      short* dh = hx_hi + zrow*HXW + 128 + zcb;
      short* dl = hx_lo + zrow*HXW + 128 + zcb;
      *(short8*)(dh)     = *(short8*)(hb);
      *(short8*)(dh + 8) = *(short8*)(hb + 8);
      *(short8*)(dl)     = *(short8*)(lb);
      *(short8*)(dl + 8) = *(short8*)(lb + 8);
    }
    __syncthreads();  // S5: h(t+1) ready; also orders red2 read(t) vs write(t+1)

    // loop: next z-GEMM reads hx (h written pre-S5, x staged pre-S4-ish);
    // red next written pre-S1 (last read post-S1 this step, S4/S5 between).
  }

  // ---- epilogue: output for the final step t = S_LEN-1 (uses h(S)) ----
  out_gemm_mfma(hx_hi, hx_lo, who_hi, who_lo, red2, wv, nn, quad);
  __syncthreads();
  out_write(red2, sbho, out, r0, oc0, S_LEN - 1, tid);
}

extern "C" void kernel_launch(void* const* d_in, const int* in_sizes, int n_in,
                              void* d_out, int out_size, void* d_ws, size_t ws_size,
                              hipStream_t stream) {
  const float* X     = (const float*)d_in[0];
  const float* W_ih  = (const float*)d_in[1];
  // d_in[2] = b_ih: unused (per-column constant cancels exactly in BatchNorm)
  const float* W_ho  = (const float*)d_in[3];
  const float* b_ho  = (const float*)d_in[4];
  const float* gamma = (const float*)d_in[5];
  const float* beta  = (const float*)d_in[6];
  float* out = (float*)d_out;

  u64* part = (u64*)d_ws;                 // tagged partials (two parities)
  u64* zbuf = part + PART_U64;            // tagged z exchange (two parities)

  init_tags<<<dim3(512), dim3(256), 0, stream>>>((u64*)d_ws);

  hipFuncSetAttribute((const void*)rec_kernel,
                      hipFuncAttributeMaxDynamicSharedMemorySize, SMEM_BYTES);

  // 128 blocks, 1 per CU (LDS-limited) on a 256-CU idle device -> all
  // co-resident; tagged-data polls provide all cross-wg ordering.
  rec_kernel<<<dim3(NBLK), dim3(NTHR), SMEM_BYTES, stream>>>(
      X, W_ih, W_ho, b_ho, gamma, beta, out, part, zbuf);
}

// Round 4
// 12983.026 us; speedup vs baseline: 2.0040x; 2.0040x over previous
//
#include <hip/hip_runtime.h>
#include <stdint.h>

// ============================================================================
// Persistent-RNN kernel for RecBlock: 2048 sequential steps, one device-wide
// flag barrier per step (BN batch statistics are the only cross-wg coupling).
//
// Partition: 128 persistent workgroups = 16 row-groups (16 batch rows each)
//            x 8 col-groups (32 hidden cols each; 16 output cols each).
// Weights (W_ih slice, W_ho slice) live in LDS for the whole kernel as
// bf16 hi/lo pairs; GEMMs run on v_mfma_f32_16x16x32_bf16 with a 3-term
// hi/lo expansion (hi*hi + hi*lo + lo*hi) for near-fp32 accuracy.
//
// v3 structure (lessons from v1 flag-barrier @13.4ms and v2 tagged @26ms):
//  * Arrival detection stays CHEAP: 256 per-WAVE flags, each consumer thread
//    polls exactly ONE word (v2's poll-everything storm congested the MALL).
//  * Exchange data (zbuf, partials) uses agent-scope (sc1) relaxed atomics:
//    coherent at the MALL, no fences, no L2 writeback/invalidate.
//  * Per-wave publish: the two data-storing waves each drain their own
//    stores (inline s_waitcnt vmcnt(0)) and store their own flag -> no
//    all-wave barrier before the flag (v1's S2 deleted).
//  * out-GEMM(t-1) is software-pipelined into the flag-wait shadow (o(t)
//    depends on h(t+1) but is a pure sink -> runs one step late, off the
//    recurrence critical path). out_write(t-1) lands after S5.
//  * reconstruct uses the r0 geometry (4 cols x 4 blocks @ stride 64,
//    short4v LDS writes): r1's 16-contiguous-col pattern tripled
//    SQ_LDS_BANK_CONFLICT (2.27e8 -> 6.63e8).
//  * (sum,sumsq) packed in one u64 -> 16 gather loads/thread, not 32.
//  * Barriers per step: S1 (z reduce), S3 (flags), S4 (stats), S5 (h ready).
//
// b_ih is omitted: a per-column constant cancels exactly in (z - mean(z)).
// ============================================================================

#define S_LEN 2048
#define BATCH 256
#define NIN   128
#define HID   256
#define NOUT  128

#define NBLK  128   // 16 row-groups x 8 col-groups (1 block/CU by LDS)
#define NTHR  256   // 4 waves
#define NR    16    // batch rows per wg
#define NC    32    // z columns per wg
#define NO    16    // output columns per wg

#define HXW   392   // padded k-stride (shorts) for hx and W_ih slices (384+8)
#define WHOW  264   // padded k-stride (shorts) for W_ho slice (256+8)

#define SPIN_MAX (1u<<16)   // bounded spin: converts any protocol bug into a
                            // wrong answer instead of a hung container

typedef short short8  __attribute__((ext_vector_type(8)));
typedef short short4v __attribute__((ext_vector_type(4)));
typedef float float4v __attribute__((ext_vector_type(4)));
typedef unsigned long long u64;

// LDS layout (in shorts for the bf16 region, floats after)
#define HXHI_OFF  0
#define HXLO_OFF  (16*HXW)
#define WHI_OFF   (2*16*HXW)
#define WLO_OFF   (2*16*HXW + 32*HXW)
#define WHOHI_OFF (2*16*HXW + 2*32*HXW)
#define WHOLO_OFF (WHOHI_OFF + 16*WHOW)
#define SHORTS_TOTAL (WHOLO_OFF + 16*WHOW)      // 46080 shorts = 92160 B
#define RED_F 1088                               // 4 x 16 x 17 floats
#define SMEM_BYTES (SHORTS_TOTAL*2 + (2*RED_F + 256 + 256 + 16)*4)  // 102976 B

// workspace layout:
//   flags:    256 x u32 @ stride 32 u32 (128 B)   = 32 KB  (monotonic stamps)
//   partials: [2][16 rowg][256 col] u64 (s|q)     = 64 KB
//   zbuf:     [2][256 row][256 col] f32           = 512 KB
#define FLAGS_U32 (256*32)
#define PART_U64  (2*16*256)

#define MFMA(a,b,c) __builtin_amdgcn_mfma_f32_16x16x32_bf16(a,b,c,0,0,0)

#define AG_ST(p, v) __hip_atomic_store((p), (v), __ATOMIC_RELAXED, __HIP_MEMORY_SCOPE_AGENT)
#define AG_LD(p)    __hip_atomic_load((p), __ATOMIC_RELAXED, __HIP_MEMORY_SCOPE_AGENT)

__device__ __forceinline__ u64 pack2f(float s, float q) {
  return (u64)__float_as_uint(s) | ((u64)__float_as_uint(q) << 32);
}
__device__ __forceinline__ float lo_f(u64 v) { return __uint_as_float((unsigned)v); }
__device__ __forceinline__ float hi_f(u64 v) { return __uint_as_float((unsigned)(v >> 32)); }

__device__ __forceinline__ short f2bf(float f) {
  unsigned u = __float_as_uint(f);
  unsigned r = (u + 0x7fffu + ((u >> 16) & 1u)) >> 16;  // RNE
  return (short)r;
}
__device__ __forceinline__ float bf2f(short s) {
  return __uint_as_float(((unsigned)(unsigned short)s) << 16);
}
__device__ __forceinline__ float gelu_f(float x) {
  return 0.5f * x * (1.0f + erff(x * 0.70710678118654752f));
}

// stage X[:, t, :] slice (16 rows x 128) into hx bf16 hi/lo
__device__ __forceinline__ void stage_x(const float* __restrict__ X,
                                        short* hx_hi, short* hx_lo,
                                        int r0, int t, int tid) {
  int row = tid >> 4;           // 0..15
  int k0  = (tid & 15) * 8;     // 0..120
  const float* xp = X + ((size_t)(r0 + row) * S_LEN + t) * NIN + k0;
  float4v a = *(const float4v*)xp;
  float4v b = *(const float4v*)(xp + 4);
  short8 hi, lo;
#pragma unroll
  for (int j = 0; j < 4; ++j) {
    short h1 = f2bf(a[j]); hi[j] = h1; lo[j] = f2bf(a[j] - bf2f(h1));
  }
#pragma unroll
  for (int j = 0; j < 4; ++j) {
    short h1 = f2bf(b[j]); hi[4+j] = h1; lo[4+j] = f2bf(b[j] - bf2f(h1));
  }
  *(short8*)(hx_hi + row*HXW + k0) = hi;
  *(short8*)(hx_lo + row*HXW + k0) = lo;
}

// out-GEMM MFMA phase: o-partial for K-quarter wv -> red2 (reads hx h-region)
__device__ __forceinline__ void out_gemm_mfma(const short* hx_hi, const short* hx_lo,
                                              const short* who_hi, const short* who_lo,
                                              float* red2, int wv, int nn, int quad) {
  float4v oacc = {0.f, 0.f, 0.f, 0.f};
  const short* arow_hi = hx_hi + nn*HXW + 128;
  const short* arow_lo = hx_lo + nn*HXW + 128;
  const short* brow_hi = who_hi + nn*WHOW;
  const short* brow_lo = who_lo + nn*WHOW;
  int kb = wv*64 + quad*8;
#pragma unroll
  for (int ks = 0; ks < 2; ++ks) {
    short8 ah = *(const short8*)(arow_hi + kb);
    short8 al = *(const short8*)(arow_lo + kb);
    short8 bh = *(const short8*)(brow_hi + kb);
    short8 bl = *(const short8*)(brow_lo + kb);
    oacc = MFMA(ah, bh, oacc);
    oacc = MFMA(ah, bl, oacc);
    oacc = MFMA(al, bh, oacc);
    kb += 32;
  }
#pragma unroll
  for (int i = 0; i < 4; ++i) red2[wv*272 + (quad*4 + i)*17 + nn] = oacc[i];
}

__device__ __forceinline__ void out_write(const float* red2, const float* sbho,
                                          float* __restrict__ out,
                                          int r0, int oc0, int t, int tid) {
  int row = tid >> 4, col = tid & 15;
  float v = red2[0*272 + row*17 + col] + red2[1*272 + row*17 + col]
          + red2[2*272 + row*17 + col] + red2[3*272 + row*17 + col]
          + sbho[col];
  out[((size_t)(r0 + row) * S_LEN + t) * NOUT + oc0 + col] = gelu_f(v);
}

__global__ void init_flags(unsigned* flags) {
  // agent-scope stores so the zeros land at the MALL (where rec_kernel's
  // sc1 polls read), not as dirty lines in one XCD's L2.
  AG_ST(flags + (size_t)threadIdx.x * 32, 0u);
}

__global__ void __launch_bounds__(NTHR, 1)
rec_kernel(const float* __restrict__ X, const float* __restrict__ W_ih,
           const float* __restrict__ W_ho, const float* __restrict__ b_ho,
           const float* __restrict__ gamma, const float* __restrict__ beta,
           float* __restrict__ out, unsigned* __restrict__ flags,
           u64* __restrict__ part, float* __restrict__ zbuf)
{
  extern __shared__ char smemraw[];
  short* sh      = (short*)smemraw;
  short* hx_hi   = sh + HXHI_OFF;   // [16][HXW]  k: 0..127 = x_t, 128..383 = h_t
  short* hx_lo   = sh + HXLO_OFF;
  short* w_hi    = sh + WHI_OFF;    // [32][HXW]  W_ih rows c0..c0+31
  short* w_lo    = sh + WLO_OFF;
  short* who_hi  = sh + WHOHI_OFF;  // [16][WHOW] W_ho rows oc0..oc0+15
  short* who_lo  = sh + WHOLO_OFF;
  float* red     = (float*)(sh + SHORTS_TOTAL); // z-GEMM cross-wave reduce
  float* red2    = red + RED_F;     // [4][16][17] out-GEMM reduce (own region)
  float* sscale  = red2 + RED_F;    // [256] BN scale per column
  float* sshift  = sscale + 256;    // [256] BN shift per column
  float* sbho    = sshift + 256;    // [16]

  const int tid   = threadIdx.x;
  const int rowg  = blockIdx.x >> 3;   // 0..15
  const int colg  = blockIdx.x & 7;    // 0..7
  const int r0    = rowg * NR;
  const int c0    = colg * NC;
  const int oc0   = colg * NO;
  const int wv    = tid >> 6;          // wave 0..3
  const int lane  = tid & 63;
  const int nn    = lane & 15;         // MFMA m / n index
  const int quad  = lane >> 4;         // MFMA k-group / row-group
  const int sub   = wv >> 1;           // z col-subtile 0/1
  const int khalf = wv & 1;            // K half for z-GEMM

  // ---- one-time init: stage weight slices into LDS as bf16 hi/lo ----
  for (int idx = tid; idx < NC * 384; idx += NTHR) {
    int r = idx / 384, j = idx % 384;
    float w = W_ih[(size_t)(c0 + r) * 384 + j];
    short hi = f2bf(w);
    w_hi[r*HXW + j] = hi;
    w_lo[r*HXW + j] = f2bf(w - bf2f(hi));
  }
  for (int idx = tid; idx < NO * 256; idx += NTHR) {
    int r = idx / 256, j = idx % 256;
    float w = W_ho[(size_t)(oc0 + r) * 256 + j];
    short hi = f2bf(w);
    who_hi[r*WHOW + j] = hi;
    who_lo[r*WHOW + j] = f2bf(w - bf2f(hi));
  }
  if (tid < NO) sbho[tid] = b_ho[oc0 + tid];
  // h0 = 0: zero the h region of hx (k in [128, 392))
  for (int idx = tid; idx < 16 * 33; idx += NTHR) {
    int row = idx / 33, k0 = 128 + (idx % 33) * 8;
    short8 z8 = {0,0,0,0,0,0,0,0};
    *(short8*)(hx_hi + row*HXW + k0) = z8;
    *(short8*)(hx_lo + row*HXW + k0) = z8;
  }
  stage_x(X, hx_hi, hx_lo, r0, 0, tid);

  const float g_gamma = gamma[tid];   // loop-invariant (tid = BN column)
  const float g_beta  = beta[tid];
  __syncthreads();

  for (int t = 0; t < S_LEN; ++t) {
    const int p = t & 1;
    u64*   partp = part + (size_t)p * (16*256);
    float* zbp   = zbuf + (size_t)p * (BATCH*HID);
    const unsigned tag = (unsigned)(t + 1);

    // ---- z-GEMM: z[r0..r0+15][c0+sub*16 .. +16) over K half ----
    float4v acc = {0.f, 0.f, 0.f, 0.f};
    {
      const short* arow_hi = hx_hi + nn*HXW;             // A row m = nn
      const short* arow_lo = hx_lo + nn*HXW;
      const short* brow_hi = w_hi + (sub*16 + nn)*HXW;   // B col n = nn
      const short* brow_lo = w_lo + (sub*16 + nn)*HXW;
      int kb = khalf*192 + quad*8;
#pragma unroll
      for (int ks = 0; ks < 6; ++ks) {
        short8 ah = *(const short8*)(arow_hi + kb);
        short8 al = *(const short8*)(arow_lo + kb);
        short8 bh = *(const short8*)(brow_hi + kb);
        short8 bl = *(const short8*)(brow_lo + kb);
        acc = MFMA(ah, bh, acc);
        acc = MFMA(ah, bl, acc);
        acc = MFMA(al, bh, acc);
        kb += 32;
      }
    }
    if (khalf == 1) {   // publish K-half-1 partial for cross-wave reduce
#pragma unroll
      for (int i = 0; i < 4; ++i) red[sub*272 + (quad*4 + i)*17 + nn] = acc[i];
    }
    __syncthreads();  // S1
    if (khalf == 0) {   // waves 0,2: finish z, publish, drain, set own flag
#pragma unroll
      for (int i = 0; i < 4; ++i) acc[i] += red[sub*272 + (quad*4 + i)*17 + nn];
      // z tile -> MALL (sc1 f32 stores)
      float* zb = zbp + (size_t)(r0 + quad*4) * HID + (c0 + sub*16 + nn);
#pragma unroll
      for (int i = 0; i < 4; ++i) AG_ST(zb + i*HID, acc[i]);
      // per-column partial sums over our 16 rows
      float s = acc[0] + acc[1] + acc[2] + acc[3];
      float q = acc[0]*acc[0] + acc[1]*acc[1] + acc[2]*acc[2] + acc[3]*acc[3];
      s += __shfl_down(s, 32);  q += __shfl_down(q, 32);
      s += __shfl_down(s, 16);  q += __shfl_down(q, 16);
      if (lane < 16) {
        int c = c0 + sub*16 + lane;
        AG_ST(partp + (size_t)rowg*256 + c, pack2f(s, q));
      }
      // per-wave drain + flag: no all-wave barrier needed before publish
      asm volatile("s_waitcnt vmcnt(0)" ::: "memory");
      if (lane == 0)
        AG_ST(flags + ((size_t)blockIdx.x * 2 + sub) * 32, tag);
    }

    // ---- flag-wait shadow: pipelined out-GEMM(t-1) + X prefetch ----
    // out-GEMM reads hx h-region = h(t) (stable until reconstruct, post-S4);
    // red2 last read at out_write(t-2), separated by S1 above.
    if (t > 0)
      out_gemm_mfma(hx_hi, hx_lo, who_hi, who_lo, red2, wv, nn, quad);
    if (t + 1 < S_LEN) stage_x(X, hx_hi, hx_lo, r0, t + 1, tid);

    // ---- distributed flag wait: each thread polls exactly ONE word ----
    {
      const unsigned* fp = flags + (size_t)tid * 32;   // (wg tid>>1, wave-half tid&1)
      unsigned spin = 0;
      while (AG_LD(fp) < tag && ++spin < SPIN_MAX)
        __builtin_amdgcn_s_sleep(1);
    }
    __syncthreads();  // S3

    // ---- gather: zbuf first (latency hides under stats), r0 geometry ----
    const int zrow = tid >> 4;           // row within our 16
    const int zcb  = (tid & 15) * 4;     // 4-col blocks at stride 64
    u64 zt[4][2];
#pragma unroll
    for (int c4 = 0; c4 < 4; ++c4) {
      const u64* zp = (const u64*)(zbp + (size_t)(r0 + zrow) * HID + zcb + c4*64);
      zt[c4][0] = AG_LD(zp);
      zt[c4][1] = AG_LD(zp + 1);
    }
    // partials: 16 packed u64 loads (this thread = BN column tid)
    {
      float sA = 0.f, sB = 0.f;
      u64 pv[16];
#pragma unroll
      for (int rg = 0; rg < 16; ++rg) pv[rg] = AG_LD(partp + (size_t)rg*256 + tid);
#pragma unroll
      for (int rg = 0; rg < 16; ++rg) { sA += lo_f(pv[rg]); sB += hi_f(pv[rg]); }
      float mu   = sA * (1.0f/256.0f);
      float var  = sB * (1.0f/256.0f) - mu*mu;    // biased, matches BN training
      float rstd = rsqrtf(var + 1e-5f);
      float g    = g_gamma * rstd;
      sscale[tid] = g;
      sshift[tid] = g_beta - mu * g;
    }
    __syncthreads();  // S4 (also orders red2 writes vs out_write below)

    // ---- reconstruct h(t+1): BN + exact GELU, r0 LDS-write geometry ----
    {
#pragma unroll
      for (int c4 = 0; c4 < 4; ++c4) {
        int col = zcb + c4*64;
        short4v h4, l4;
#pragma unroll
        for (int j = 0; j < 4; ++j) {
          float z  = (j & 1) ? hi_f(zt[c4][j >> 1]) : lo_f(zt[c4][j >> 1]);
          float zn = z * sscale[col + j] + sshift[col + j];
          float h  = gelu_f(zn);
          short hh = f2bf(h);
          h4[j] = hh; l4[j] = f2bf(h - bf2f(hh));
        }
        *(short4v*)(hx_hi + zrow*HXW + 128 + col) = h4;
        *(short4v*)(hx_lo + zrow*HXW + 128 + col) = l4;
      }
    }
    __syncthreads();  // S5: h(t+1) ready for next z-GEMM

    // ---- off-critical-path: finish o(t-1) (red2 reads done before next S1) ----
    if (t > 0) out_write(red2, sbho, out, r0, oc0, t - 1, tid);
  }

  // ---- epilogue: o(S_LEN-1) from h(S_LEN) ----
  __syncthreads();                       // out_write(2046) reads vs red2 writes
  out_gemm_mfma(hx_hi, hx_lo, who_hi, who_lo, red2, wv, nn, quad);
  __syncthreads();
  out_write(red2, sbho, out, r0, oc0, S_LEN - 1, tid);
}

extern "C" void kernel_launch(void* const* d_in, const int* in_sizes, int n_in,
                              void* d_out, int out_size, void* d_ws, size_t ws_size,
                              hipStream_t stream) {
  const float* X     = (const float*)d_in[0];
  const float* W_ih  = (const float*)d_in[1];
  // d_in[2] = b_ih: unused (per-column constant cancels exactly in BatchNorm)
  const float* W_ho  = (const float*)d_in[3];
  const float* b_ho  = (const float*)d_in[4];
  const float* gamma = (const float*)d_in[5];
  const float* beta  = (const float*)d_in[6];
  float* out = (float*)d_out;

  unsigned* flags = (unsigned*)d_ws;                  // 32 KB (256 x 128 B)
  u64* part = (u64*)((char*)d_ws + FLAGS_U32*4);      // 64 KB (2 parities)
  float* zbuf = (float*)(part + PART_U64);            // 512 KB (2 parities)

  init_flags<<<dim3(1), dim3(256), 0, stream>>>(flags);

  hipFuncSetAttribute((const void*)rec_kernel,
                      hipFuncAttributeMaxDynamicSharedMemorySize, SMEM_BYTES);

  // 128 blocks, 1 per CU (LDS-limited) on a 256-CU idle device -> all
  // co-resident; per-wave monotonic flags handle grid sync.
  rec_kernel<<<dim3(NBLK), dim3(NTHR), SMEM_BYTES, stream>>>(
      X, W_ih, W_ho, b_ho, gamma, beta, out, flags, part, zbuf);
}